// Round 7
// baseline (840.991 us; speedup 1.0000x reference)
//
#include <hip/hip_runtime.h>
#include <cstddef>
#include <cstdint>
#include <math.h>

#define N_NODES 50000
#define N_EDGES 1600000
#define IN_C 512
#define HID_C 256
#define OUT_C 50
#define PAD_C 64
#define HALF_C 32
#define NUM_LAYERS 10
#define NBUCK 98          // ceil(50000/512) row-buckets
#define BSHIFT 9          // 512 rows per bucket
#define BCAP 20480        // mean 16327 + 32 sigma — overflow unreachable
#define PHB_CHUNK 8192    // edges per block in bucket_scatter
#define PHB_BLOCKS 196    // ceil(N_EDGES / PHB_CHUNK)

typedef __attribute__((ext_vector_type(8))) short short8;    // 8 bf16 (4 VGPRs)
typedef __attribute__((ext_vector_type(4))) float floatx4;   // MFMA C/D frag

__device__ inline unsigned short f2bf(float f) {             // RNE fp32->bf16
    unsigned int u = __float_as_uint(f);
    u += 0x7fffu + ((u >> 16) & 1u);
    return (unsigned short)(u >> 16);
}

// ---------------------------------------------------------------------------
// W1 [512,256] fp32  ->  Wt [256,512] bf16   (LDS-tiled transpose)
// ---------------------------------------------------------------------------
__global__ __launch_bounds__(256) void transpose_w1(const float* __restrict__ W1,
                                                    unsigned short* __restrict__ Wt) {
    __shared__ float tile[32][33];
    int bx = blockIdx.x;               // k-tile (16)
    int by = blockIdx.y;               // n-tile (8)
    int tx = threadIdx.x & 31, ty = threadIdx.x >> 5;   // 32 x 8
#pragma unroll
    for (int i = 0; i < 32; i += 8)
        tile[ty + i][tx] = W1[(bx * 32 + ty + i) * HID_C + by * 32 + tx];
    __syncthreads();
#pragma unroll
    for (int i = 0; i < 32; i += 8)
        Wt[(size_t)(by * 32 + ty + i) * IN_C + bx * 32 + tx] = f2bf(tile[tx][ty + i]);
}

// ---------------------------------------------------------------------------
// GEMM1 MFMA: h_hid[M,256] = relu(x[M,512] @ W1 + b1)
// 64x128 tile, BK=32, bf16 16x16x32 MFMA, register-prefetch double buffering.
// ---------------------------------------------------------------------------
__global__ __launch_bounds__(256) void gemm1_mfma(const float* __restrict__ A,
                                                  const unsigned short* __restrict__ Wt,
                                                  const float* __restrict__ bias,
                                                  float* __restrict__ C) {
    __shared__ unsigned short As[64 * 32];    // [m][k] k-contiguous
    __shared__ unsigned short Bs[128 * 32];   // [n][k] k-contiguous
    const int tid = threadIdx.x;
    const int wave = tid >> 6, lane = tid & 63;
    const int quad = lane >> 4, l16 = lane & 15;
    const int m0 = blockIdx.x * 64, n0 = blockIdx.y * 128;
    const int wm = (wave >> 1) * 32, wn = (wave & 1) * 64;

    floatx4 acc[2][4];
#pragma unroll
    for (int i = 0; i < 2; ++i)
#pragma unroll
        for (int j = 0; j < 4; ++j) acc[i][j] = (floatx4){0.f, 0.f, 0.f, 0.f};

    float4  pa[2];
    ushort4 pb[4];

    auto fetch = [&](int k0) {
#pragma unroll
        for (int j = 0; j < 2; ++j) {
            int row = (j * 256 + tid) >> 3, c = (j * 256 + tid) & 7;
            int gr = m0 + row;
            pa[j] = make_float4(0.f, 0.f, 0.f, 0.f);
            if (gr < N_NODES)
                pa[j] = *(const float4*)(A + (size_t)gr * IN_C + k0 + c * 4);
        }
#pragma unroll
        for (int j = 0; j < 4; ++j) {
            int row = (j * 256 + tid) >> 3, c = (j * 256 + tid) & 7;
            pb[j] = *(const ushort4*)(Wt + (size_t)(n0 + row) * IN_C + k0 + c * 4);
        }
    };

    fetch(0);
    for (int k0 = 0; k0 < IN_C; k0 += 32) {
        __syncthreads();
#pragma unroll
        for (int j = 0; j < 2; ++j) {
            int row = (j * 256 + tid) >> 3, c = (j * 256 + tid) & 7;
            ushort4 u;
            u.x = f2bf(pa[j].x); u.y = f2bf(pa[j].y);
            u.z = f2bf(pa[j].z); u.w = f2bf(pa[j].w);
            *(ushort4*)&As[row * 32 + c * 4] = u;
        }
#pragma unroll
        for (int j = 0; j < 4; ++j) {
            int row = (j * 256 + tid) >> 3, c = (j * 256 + tid) & 7;
            *(ushort4*)&Bs[row * 32 + c * 4] = pb[j];
        }
        __syncthreads();
        if (k0 + 32 < IN_C) fetch(k0 + 32);   // in flight during MFMA phase

        short8 af[2], bf[4];
#pragma unroll
        for (int nt = 0; nt < 4; ++nt)
            bf[nt] = *(const short8*)&Bs[(wn + nt * 16 + l16) * 32 + quad * 8];
#pragma unroll
        for (int mt = 0; mt < 2; ++mt)
            af[mt] = *(const short8*)&As[(wm + mt * 16 + l16) * 32 + quad * 8];
#pragma unroll
        for (int mt = 0; mt < 2; ++mt)
#pragma unroll
            for (int nt = 0; nt < 4; ++nt)
                acc[mt][nt] = __builtin_amdgcn_mfma_f32_16x16x32_bf16(af[mt], bf[nt],
                                                                      acc[mt][nt], 0, 0, 0);
    }

    // epilogue: row = quad*4+r, col = l16 (R3-verified mapping)
#pragma unroll
    for (int nt = 0; nt < 4; ++nt) {
        int n = n0 + wn + nt * 16 + l16;
        float bn = bias[n];
#pragma unroll
        for (int mt = 0; mt < 2; ++mt) {
#pragma unroll
            for (int r = 0; r < 4; ++r) {
                int m = m0 + wm + mt * 16 + quad * 4 + r;
                if (m < N_NODES) {
                    float v = acc[mt][nt][r] + bn;
                    C[(size_t)m * HID_C + n] = v > 0.f ? v : 0.f;
                }
            }
        }
    }
}

// ---------------------------------------------------------------------------
// pad W2 [256,50] -> Wp [256,64] (zeros), b2 -> bp[64]
// ---------------------------------------------------------------------------
__global__ void pad_w2(const float* __restrict__ W2, const float* __restrict__ b2,
                       float* __restrict__ Wp, float* __restrict__ bp) {
    int idx = blockIdx.x * blockDim.x + threadIdx.x;
    if (idx < HID_C * PAD_C) {
        int k = idx >> 6, j = idx & 63;
        Wp[idx] = (j < OUT_C) ? W2[k * OUT_C + j] : 0.f;
    }
    if (idx < PAD_C) bp[idx] = (idx < OUT_C) ? b2[idx] : 0.f;
}

// ---------------------------------------------------------------------------
// GEMM2 tiled: h0 = H[M,256] @ Wp[256,64] + bp.
// Writes fp32 full rows (h0f, stride 64) AND bf16 channel-halves (h0bA/h0bB).
// ---------------------------------------------------------------------------
__global__ __launch_bounds__(256) void gemm2_tiled(const float* __restrict__ H,
                                                   const float* __restrict__ Wp,
                                                   const float* __restrict__ bp,
                                                   float* __restrict__ h0f,
                                                   unsigned short* __restrict__ h0bA,
                                                   unsigned short* __restrict__ h0bB) {
    __shared__ float As[16][68];
    __shared__ float Bs[16][64];
    const int tid = threadIdx.x;
    const int tx = tid & 15;
    const int ty = tid >> 4;
    const int m0 = blockIdx.x * 64;

    float acc[4][4];
#pragma unroll
    for (int i = 0; i < 4; ++i)
#pragma unroll
        for (int j = 0; j < 4; ++j) acc[i][j] = 0.f;

    const int arow = tid >> 2;
    const int akk  = (tid & 3) << 2;
    const int brow = tid >> 4;
    const int bcol = (tid & 15) << 2;

    for (int k0 = 0; k0 < HID_C; k0 += 16) {
        float4 av = make_float4(0.f, 0.f, 0.f, 0.f);
        int gr = m0 + arow;
        if (gr < N_NODES)
            av = *(const float4*)(H + (size_t)gr * HID_C + k0 + akk);
        As[akk + 0][arow] = av.x;
        As[akk + 1][arow] = av.y;
        As[akk + 2][arow] = av.z;
        As[akk + 3][arow] = av.w;
        float4 bv = *(const float4*)(Wp + (size_t)(k0 + brow) * PAD_C + bcol);
        *(float4*)&Bs[brow][bcol] = bv;
        __syncthreads();

#pragma unroll
        for (int kk = 0; kk < 16; ++kk) {
            float a[4], b[4];
#pragma unroll
            for (int i = 0; i < 4; ++i) a[i] = As[kk][ty * 4 + i];
#pragma unroll
            for (int j = 0; j < 4; ++j) b[j] = Bs[kk][tx * 4 + j];
#pragma unroll
            for (int i = 0; i < 4; ++i)
#pragma unroll
                for (int j = 0; j < 4; ++j) acc[i][j] = fmaf(a[i], b[j], acc[i][j]);
        }
        __syncthreads();
    }

#pragma unroll
    for (int i = 0; i < 4; ++i) {
        int r = m0 + ty * 4 + i;
        if (r >= N_NODES) continue;
#pragma unroll
        for (int j = 0; j < 4; ++j) {
            int c = tx * 4 + j;
            float v = acc[i][j] + bp[c];
            h0f[(size_t)r * PAD_C + c] = v;
            if (c < HALF_C) h0bA[(size_t)r * HALF_C + c] = f2bf(v);
            else            h0bB[(size_t)r * HALF_C + (c - HALF_C)] = f2bf(v);
        }
    }
}

// ---------------------------------------------------------------------------
// CSR build v3: bucket_scatter -> 98-scan -> fused per-bucket hist/scan/
// scatter (all row-local work in LDS; no 50000-bin global histogram, no
// global fill atomics). R6's hist_kernel was 72 us with 50 MB of atomic
// write-through amplification — deleted entirely.
// ---------------------------------------------------------------------------
// Phase A: bin edges into row-buckets. Payload 8 B: (localrow<<17 | col, w).
__global__ __launch_bounds__(256) void bucket_scatter(const int* __restrict__ erow,
                                                      const int* __restrict__ ecol,
                                                      const float* __restrict__ ew,
                                                      int* __restrict__ bfill,
                                                      uint2* __restrict__ buckets) {
    __shared__ int lcnt[NBUCK];
    __shared__ int lbase[NBUCK];
    const int t = threadIdx.x;
    for (int b = t; b < NBUCK; b += 256) lcnt[b] = 0;
    __syncthreads();
    const int e0 = blockIdx.x * PHB_CHUNK;
    const int e1 = min(e0 + PHB_CHUNK, N_EDGES);
    for (int e = e0 + t; e < e1; e += 256)
        atomicAdd(&lcnt[erow[e] >> BSHIFT], 1);
    __syncthreads();
    for (int b = t; b < NBUCK; b += 256) {
        lbase[b] = atomicAdd(&bfill[b], lcnt[b]);
        lcnt[b] = 0;
    }
    __syncthreads();
    for (int e = e0 + t; e < e1; e += 256) {
        int r = erow[e];
        int b = r >> BSHIFT;
        int o = atomicAdd(&lcnt[b], 1);
        int idx = lbase[b] + o;
        if (idx < BCAP) {   // BCAP = mean + 32 sigma: always true
            unsigned packed = ((unsigned)(r - (b << BSHIFT)) << 17) | (unsigned)ecol[e];
            buckets[(size_t)b * BCAP + idx] = make_uint2(packed, __float_as_uint(ew[e]));
        }
    }
}

// Phase B: exclusive scan of 98 bucket counts -> bucket bases; total rowptr.
__global__ __launch_bounds__(128) void bucket_scan(const int* __restrict__ bfill,
                                                   int* __restrict__ bbase,
                                                   int* __restrict__ rowptr) {
    __shared__ int sd[128];
    int t = threadIdx.x;
    int v = (t < NBUCK) ? min(bfill[t], BCAP) : 0;
    sd[t] = v;
    __syncthreads();
    for (int off = 1; off < 128; off <<= 1) {
        int x = (t >= off) ? sd[t - off] : 0;
        __syncthreads();
        sd[t] += x;
        __syncthreads();
    }
    if (t < NBUCK) bbase[t] = sd[t] - v;
    if (t == NBUCK - 1) {
        bbase[NBUCK] = sd[t];
        rowptr[N_NODES] = sd[t];
    }
}

// Phase C (per bucket): LDS hist(512) -> LDS scan -> rowptr + scatter into
// the bucket's contiguous CSR span (~130 KB, L2-resident writes).
__global__ __launch_bounds__(256) void bucket_csr(const uint2* __restrict__ buckets,
                                                  const int* __restrict__ bfill,
                                                  const int* __restrict__ bbase,
                                                  int* __restrict__ rowptr,
                                                  uint2* __restrict__ edges) {
    __shared__ int hist[512];
    __shared__ int excl[512];
    __shared__ int psum[256];
    const int b = blockIdx.x;
    const int t = threadIdx.x;
    const int n = min(bfill[b], BCAP);
    const uint2* bk = buckets + (size_t)b * BCAP;

    hist[t] = 0; hist[t + 256] = 0;
    __syncthreads();
    for (int i = t; i < n; i += 256)
        atomicAdd(&hist[bk[i].x >> 17], 1);
    __syncthreads();
    // scan 512 bins with 256 threads: pairwise + Hillis-Steele
    int a0 = hist[2 * t], a1 = hist[2 * t + 1];
    psum[t] = a0 + a1;
    __syncthreads();
    for (int off = 1; off < 256; off <<= 1) {
        int x = (t >= off) ? psum[t - off] : 0;
        __syncthreads();
        psum[t] += x;
        __syncthreads();
    }
    int pe = psum[t] - (a0 + a1);    // exclusive over pairs
    excl[2 * t] = pe;
    excl[2 * t + 1] = pe + a0;
    __syncthreads();
    const int base = bbase[b];
    // rowptr
#pragma unroll
    for (int k = 0; k < 2; ++k) {
        int lr = t + k * 256;
        int r = (b << BSHIFT) + lr;
        if (r < N_NODES) rowptr[r] = base + excl[lr];
    }
    // reset fill (reuse hist)
    hist[t] = 0; hist[t + 256] = 0;
    __syncthreads();
    // scatter
    for (int i = t; i < n; i += 256) {
        uint2 ed = bk[i];
        int lr = ed.x >> 17;
        int pos = base + excl[lr] + atomicAdd(&hist[lr], 1);
        edges[pos] = make_uint2(ed.x & 0x1FFFFu, ed.y);
    }
}

// ---------------------------------------------------------------------------
// Propagation, channel-split half-pass: h stored as two 3.2 MB halves
// (32 bf16 ch, 64 B rows) so each pass's gather working set fits a 4 MB
// per-XCD L2. 4 lanes x 16 B cover one row -> ONE gather instruction serves
// 16 edges. SpMM is channel-diagonal: pass reads hin-half, writes hout-half.
// xor(4/8/16/32) butterfly all-reduces the 16 edge slots.
// ---------------------------------------------------------------------------
template <bool LAST>
__global__ __launch_bounds__(256) void prop_half(const int* __restrict__ rowptr,
                                                 const uint2* __restrict__ edges,
                                                 const unsigned short* __restrict__ hinH,
                                                 const float* __restrict__ h0f, int sel,
                                                 unsigned short* __restrict__ houtH,
                                                 float* __restrict__ houtF) {
    int wid = (blockIdx.x * blockDim.x + threadIdx.x) >> 6;
    if (wid >= N_NODES) return;
    int lane = threadIdx.x & 63;
    int slot = lane >> 2;     // edge slot, 16 per instruction
    int lc   = lane & 3;      // 16 B chunk: channels 8lc .. 8lc+7 of the half
    int s = rowptr[wid], e = rowptr[wid + 1];

    float acc0[8], acc1[8];
#pragma unroll
    for (int k = 0; k < 8; ++k) { acc0[k] = 0.f; acc1[k] = 0.f; }

    int i = s;
    for (; i + 32 <= e; i += 32) {
        uint2 cw0 = edges[i + slot];
        uint2 cw1 = edges[i + 16 + slot];
        uint4 hv0 = *(const uint4*)((const char*)hinH + ((size_t)cw0.x << 6) + lc * 16);
        uint4 hv1 = *(const uint4*)((const char*)hinH + ((size_t)cw1.x << 6) + lc * 16);
        float w0 = __uint_as_float(cw0.y);
        float w1 = __uint_as_float(cw1.y);
        acc0[0] = fmaf(w0, __uint_as_float(hv0.x << 16),         acc0[0]);
        acc0[1] = fmaf(w0, __uint_as_float(hv0.x & 0xffff0000u), acc0[1]);
        acc0[2] = fmaf(w0, __uint_as_float(hv0.y << 16),         acc0[2]);
        acc0[3] = fmaf(w0, __uint_as_float(hv0.y & 0xffff0000u), acc0[3]);
        acc0[4] = fmaf(w0, __uint_as_float(hv0.z << 16),         acc0[4]);
        acc0[5] = fmaf(w0, __uint_as_float(hv0.z & 0xffff0000u), acc0[5]);
        acc0[6] = fmaf(w0, __uint_as_float(hv0.w << 16),         acc0[6]);
        acc0[7] = fmaf(w0, __uint_as_float(hv0.w & 0xffff0000u), acc0[7]);
        acc1[0] = fmaf(w1, __uint_as_float(hv1.x << 16),         acc1[0]);
        acc1[1] = fmaf(w1, __uint_as_float(hv1.x & 0xffff0000u), acc1[1]);
        acc1[2] = fmaf(w1, __uint_as_float(hv1.y << 16),         acc1[2]);
        acc1[3] = fmaf(w1, __uint_as_float(hv1.y & 0xffff0000u), acc1[3]);
        acc1[4] = fmaf(w1, __uint_as_float(hv1.z << 16),         acc1[4]);
        acc1[5] = fmaf(w1, __uint_as_float(hv1.z & 0xffff0000u), acc1[5]);
        acc1[6] = fmaf(w1, __uint_as_float(hv1.w << 16),         acc1[6]);
        acc1[7] = fmaf(w1, __uint_as_float(hv1.w & 0xffff0000u), acc1[7]);
    }
    for (; i < e; i += 16) {    // masked tail
        int idx = i + slot;
        uint2 cw = (idx < e) ? edges[idx] : make_uint2(0u, 0u);
        float w  = (idx < e) ? __uint_as_float(cw.y) : 0.f;
        uint4 hv = *(const uint4*)((const char*)hinH + ((size_t)cw.x << 6) + lc * 16);
        acc0[0] = fmaf(w, __uint_as_float(hv.x << 16),         acc0[0]);
        acc0[1] = fmaf(w, __uint_as_float(hv.x & 0xffff0000u), acc0[1]);
        acc0[2] = fmaf(w, __uint_as_float(hv.y << 16),         acc0[2]);
        acc0[3] = fmaf(w, __uint_as_float(hv.y & 0xffff0000u), acc0[3]);
        acc0[4] = fmaf(w, __uint_as_float(hv.z << 16),         acc0[4]);
        acc0[5] = fmaf(w, __uint_as_float(hv.z & 0xffff0000u), acc0[5]);
        acc0[6] = fmaf(w, __uint_as_float(hv.w << 16),         acc0[6]);
        acc0[7] = fmaf(w, __uint_as_float(hv.w & 0xffff0000u), acc0[7]);
    }

    float r[8];
#pragma unroll
    for (int k = 0; k < 8; ++k) {
        float v = acc0[k] + acc1[k];
        v += __shfl_xor(v, 4, 64);    // butterfly over the 16 edge slots
        v += __shfl_xor(v, 8, 64);
        v += __shfl_xor(v, 16, 64);
        v += __shfl_xor(v, 32, 64);
        r[k] = v;
    }

    const float* h0p = h0f + (size_t)wid * PAD_C + sel * HALF_C + lc * 8;
    float4 h0a = *(const float4*)h0p;
    float4 h0b = *(const float4*)(h0p + 4);
    r[0] = 0.9f * r[0] + 0.1f * h0a.x;  r[1] = 0.9f * r[1] + 0.1f * h0a.y;
    r[2] = 0.9f * r[2] + 0.1f * h0a.z;  r[3] = 0.9f * r[3] + 0.1f * h0a.w;
    r[4] = 0.9f * r[4] + 0.1f * h0b.x;  r[5] = 0.9f * r[5] + 0.1f * h0b.y;
    r[6] = 0.9f * r[6] + 0.1f * h0b.z;  r[7] = 0.9f * r[7] + 0.1f * h0b.w;

    if (slot == 0) {
        if (!LAST) {
            uint4 u;
            u.x = ((unsigned)f2bf(r[1]) << 16) | f2bf(r[0]);
            u.y = ((unsigned)f2bf(r[3]) << 16) | f2bf(r[2]);
            u.z = ((unsigned)f2bf(r[5]) << 16) | f2bf(r[4]);
            u.w = ((unsigned)f2bf(r[7]) << 16) | f2bf(r[6]);
            *(uint4*)((char*)houtH + ((size_t)wid << 6) + lc * 16) = u;
        } else {
            float* op = houtF + (size_t)wid * HALF_C + lc * 8;
            *(float4*)op       = make_float4(r[0], r[1], r[2], r[3]);
            *(float4*)(op + 4) = make_float4(r[4], r[5], r[6], r[7]);
        }
    }
}

// ---------------------------------------------------------------------------
// log_softmax over 50 channels from two fp32 halves, one wave per node
// ---------------------------------------------------------------------------
__global__ __launch_bounds__(256) void logsoftmax2(const float* __restrict__ hA,
                                                   const float* __restrict__ hB,
                                                   float* __restrict__ out) {
    int wave = (blockIdx.x * blockDim.x + threadIdx.x) >> 6;
    int lane = threadIdx.x & 63;
    if (wave >= N_NODES) return;
    float v;
    if (lane < HALF_C)      v = hA[(size_t)wave * HALF_C + lane];
    else if (lane < OUT_C)  v = hB[(size_t)wave * HALF_C + lane - HALF_C];
    else                    v = -INFINITY;
    float m = v;
#pragma unroll
    for (int off = 32; off; off >>= 1) m = fmaxf(m, __shfl_xor(m, off, 64));
    float p = (lane < OUT_C) ? __expf(v - m) : 0.f;
    float ssum = p;
#pragma unroll
    for (int off = 32; off; off >>= 1) ssum += __shfl_xor(ssum, off, 64);
    if (lane < OUT_C) out[(size_t)wave * OUT_C + lane] = (v - m) - __logf(ssum);
}

// ---------------------------------------------------------------------------
extern "C" void kernel_launch(void* const* d_in, const int* in_sizes, int n_in,
                              void* d_out, int out_size, void* d_ws, size_t ws_size,
                              hipStream_t stream) {
    const float* x    = (const float*)d_in[0];
    const int*   erow = (const int*)d_in[1];
    const int*   ecol = (const int*)d_in[2];
    const float* ew   = (const float*)d_in[3];
    const float* W1   = (const float*)d_in[4];
    const float* b1   = (const float*)d_in[5];
    const float* W2   = (const float*)d_in[6];
    const float* b2   = (const float*)d_in[7];
    float* out = (float*)d_out;

    char* p = (char*)d_ws;
    auto alloc = [&](size_t bytes) {
        char* r = p;
        p += (bytes + 255) & ~(size_t)255;
        return r;
    };
    char*  h_hid_raw = alloc((size_t)N_NODES * HID_C * 4);        // 51.2 MB region
    float* h_hid  = (float*)h_hid_raw;
    float* h0f    = (float*)alloc((size_t)N_NODES * PAD_C * 4);   // 12.8 MB
    unsigned short* h0bA = (unsigned short*)alloc((size_t)N_NODES * HALF_C * 2); // 3.2 MB
    unsigned short* h0bB = (unsigned short*)alloc((size_t)N_NODES * HALF_C * 2); // 3.2 MB
    uint2* edges  = (uint2*)alloc((size_t)N_EDGES * 8);           // 12.8 MB packed CSR
    int*   rowptr = (int*)alloc((size_t)(N_NODES + 1) * 4);
    int*   bfill  = (int*)alloc((size_t)NBUCK * 4);
    int*   bbase  = (int*)alloc((size_t)(NBUCK + 1) * 4);
    float* Wp     = (float*)alloc((size_t)HID_C * PAD_C * 4);
    float* bp     = (float*)alloc((size_t)PAD_C * 4);
    unsigned short* Wt = (unsigned short*)alloc((size_t)HID_C * IN_C * 2);
    // --- aliases onto h_hid region (sequential lifetimes, stream-ordered):
    // buckets (CSR build, dead before gemm1 writes h_hid)
    uint2* buckets = (uint2*)h_hid_raw;                           // 16.1 MB
    // ping-pong halves + final fp32 halves (live after gemm2 reads h_hid)
    unsigned short* haA = (unsigned short*)h_hid_raw;                              // 3.2 MB
    unsigned short* haB = (unsigned short*)(h_hid_raw + (size_t)3200000);          // 3.2 MB
    unsigned short* hbA = (unsigned short*)(h_hid_raw + (size_t)6400000);          // 3.2 MB
    unsigned short* hbB = (unsigned short*)(h_hid_raw + (size_t)9600000);          // 3.2 MB
    float* hfA = (float*)(h_hid_raw + (size_t)12800000);                           // 6.4 MB
    float* hfB = (float*)(h_hid_raw + (size_t)19200000);                           // 6.4 MB

    hipMemsetAsync(bfill, 0, (size_t)NBUCK * 4, stream);

    // CSR build (v3: no global histogram, no global fill atomics)
    bucket_scatter<<<PHB_BLOCKS, 256, 0, stream>>>(erow, ecol, ew, bfill, buckets);
    bucket_scan<<<1, 128, 0, stream>>>(bfill, bbase, rowptr);
    bucket_csr<<<NBUCK, 256, 0, stream>>>(buckets, bfill, bbase, rowptr, edges);

    // MLP
    transpose_w1<<<dim3(IN_C / 32, HID_C / 32), 256, 0, stream>>>(W1, Wt);
    gemm1_mfma<<<dim3((N_NODES + 63) / 64, HID_C / 128), 256, 0, stream>>>(x, Wt, b1, h_hid);
    pad_w2<<<(HID_C * PAD_C + 255) / 256, 256, 0, stream>>>(W2, b2, Wp, bp);
    gemm2_tiled<<<(N_NODES + 63) / 64, 256, 0, stream>>>(h_hid, Wp, bp, h0f, h0bA, h0bB);

    // Propagation x10, two channel-half passes per layer (3.2 MB L2-resident
    // gather working set per pass)
    const int prop_blocks = (N_NODES * 64 + 255) / 256;
    const unsigned short* curA = h0bA; const unsigned short* curB = h0bB;
    unsigned short* nxtA = haA;        unsigned short* nxtB = haB;
    for (int l = 0; l < NUM_LAYERS - 1; ++l) {
        prop_half<false><<<prop_blocks, 256, 0, stream>>>(rowptr, edges, curA, h0f, 0,
                                                          nxtA, nullptr);
        prop_half<false><<<prop_blocks, 256, 0, stream>>>(rowptr, edges, curB, h0f, 1,
                                                          nxtB, nullptr);
        const unsigned short* tA = nxtA; const unsigned short* tB = nxtB;
        if (nxtA == haA) { nxtA = hbA; nxtB = hbB; } else { nxtA = haA; nxtB = haB; }
        curA = tA; curB = tB;
    }
    prop_half<true><<<prop_blocks, 256, 0, stream>>>(rowptr, edges, curA, h0f, 0,
                                                     nullptr, hfA);
    prop_half<true><<<prop_blocks, 256, 0, stream>>>(rowptr, edges, curB, h0f, 1,
                                                     nullptr, hfB);

    // log_softmax
    logsoftmax2<<<prop_blocks, 256, 0, stream>>>(hfA, hfB, out);
}

// Round 9
// 688.413 us; speedup vs baseline: 1.2216x; 1.2216x over previous
//
#include <hip/hip_runtime.h>
#include <cstddef>
#include <cstdint>
#include <math.h>

#define N_NODES 50000
#define N_EDGES 1600000
#define IN_C 512
#define HID_C 256
#define OUT_C 50
#define PAD_C 64
#define NUM_LAYERS 10
#define NBUCK 98          // ceil(50000/512) row-buckets
#define BSHIFT 9          // 512 rows per bucket
#define BCAP 20480        // mean 16327 + 32 sigma — overflow unreachable
#define PHB_CHUNK 8192    // edges per block in bucket_scatter
#define PHB_BLOCKS 196    // ceil(N_EDGES / PHB_CHUNK)
#define AP 40             // padded LDS row (shorts): 80 B stride -> 2-way max (free)

typedef __attribute__((ext_vector_type(8))) short short8;    // 8 bf16 (4 VGPRs)
typedef __attribute__((ext_vector_type(4))) float floatx4;   // MFMA C/D frag

__device__ inline unsigned short f2bf(float f) {             // RNE fp32->bf16
    unsigned int u = __float_as_uint(f);
    u += 0x7fffu + ((u >> 16) & 1u);
    return (unsigned short)(u >> 16);
}

// ---------------------------------------------------------------------------
// W1 [512,256] fp32  ->  Wt [256,512] bf16   (LDS-tiled transpose)
// ---------------------------------------------------------------------------
__global__ __launch_bounds__(256) void transpose_w1(const float* __restrict__ W1,
                                                    unsigned short* __restrict__ Wt) {
    __shared__ float tile[32][33];
    int bx = blockIdx.x;               // k-tile (16)
    int by = blockIdx.y;               // n-tile (8)
    int tx = threadIdx.x & 31, ty = threadIdx.x >> 5;   // 32 x 8
#pragma unroll
    for (int i = 0; i < 32; i += 8)
        tile[ty + i][tx] = W1[(bx * 32 + ty + i) * HID_C + by * 32 + tx];
    __syncthreads();
#pragma unroll
    for (int i = 0; i < 32; i += 8)
        Wt[(size_t)(by * 32 + ty + i) * IN_C + bx * 32 + tx] = f2bf(tile[tx][ty + i]);
}

// ---------------------------------------------------------------------------
// GEMM1 MFMA: h_hid[M,256] = relu(x[M,512] @ W1 + b1)
// 64x128 tile, BK=32, bf16 16x16x32 MFMA. 2-stage register prefetch (two
// K-tiles in flight) + AP=40 padded LDS rows (conflict-free).
// R8 BUG FIXED: B-staging now covers all 32 shorts/row (2 thr/row x 2 uint4
// = 16 shorts each); R8 staged only 16/row -> uninitialized LDS -> NaN.
// ---------------------------------------------------------------------------
__global__ __launch_bounds__(256) void gemm1_mfma(const float* __restrict__ A,
                                                  const unsigned short* __restrict__ Wt,
                                                  const float* __restrict__ bias,
                                                  float* __restrict__ C) {
    __shared__ unsigned short As[64 * AP];
    __shared__ unsigned short Bs[128 * AP];
    const int tid = threadIdx.x;
    const int wave = tid >> 6, lane = tid & 63;
    const int quad = lane >> 4, l16 = lane & 15;
    const int m0 = blockIdx.x * 64, n0 = blockIdx.y * 128;
    const int wm = (wave >> 1) * 32, wn = (wave & 1) * 64;

    floatx4 acc[2][4];
#pragma unroll
    for (int i = 0; i < 2; ++i)
#pragma unroll
        for (int j = 0; j < 4; ++j) acc[i][j] = (floatx4){0.f, 0.f, 0.f, 0.f};

    // A: 64 rows x 32 shorts; 4 thr/row, each 8 shorts (2 float4 from fp32 A)
    const int arow   = tid >> 2;
    const int achunk = (tid & 3) * 8;
    // B: 128 rows x 32 shorts; 2 thr/row, each 16 shorts (2 uint4 from Wt)
    const int brow   = tid >> 1;
    const int bchunk = (tid & 1) * 16;

    float4 pa0[2], pa1[2];
    uint4  pb0[2], pb1[2];

    auto fetch = [&](int k0, float4* pa, uint4* pb) {
        int gr = m0 + arow;
        pa[0] = make_float4(0.f, 0.f, 0.f, 0.f);
        pa[1] = pa[0];
        if (gr < N_NODES) {
            const float* base = A + (size_t)gr * IN_C + k0 + achunk;
            pa[0] = *(const float4*)base;
            pa[1] = *(const float4*)(base + 4);
        }
        const unsigned short* wb = Wt + (size_t)(n0 + brow) * IN_C + k0 + bchunk;
        pb[0] = *(const uint4*)wb;
        pb[1] = *(const uint4*)(wb + 8);
    };
    auto stage = [&](const float4* pa, const uint4* pb) {
        ushort4 u1, u2;
        u1.x = f2bf(pa[0].x); u1.y = f2bf(pa[0].y); u1.z = f2bf(pa[0].z); u1.w = f2bf(pa[0].w);
        u2.x = f2bf(pa[1].x); u2.y = f2bf(pa[1].y); u2.z = f2bf(pa[1].z); u2.w = f2bf(pa[1].w);
        *(ushort4*)&As[arow * AP + achunk]     = u1;
        *(ushort4*)&As[arow * AP + achunk + 4] = u2;
        *(uint4*)&Bs[brow * AP + bchunk]     = pb[0];
        *(uint4*)&Bs[brow * AP + bchunk + 8] = pb[1];
    };
    auto mfma_phase = [&]() {
        short8 af[2], bf[4];
#pragma unroll
        for (int nt = 0; nt < 4; ++nt)
            bf[nt] = *(const short8*)&Bs[(wn + nt * 16 + l16) * AP + quad * 8];
#pragma unroll
        for (int mt = 0; mt < 2; ++mt)
            af[mt] = *(const short8*)&As[(wm + mt * 16 + l16) * AP + quad * 8];
#pragma unroll
        for (int mt = 0; mt < 2; ++mt)
#pragma unroll
            for (int nt = 0; nt < 4; ++nt)
                acc[mt][nt] = __builtin_amdgcn_mfma_f32_16x16x32_bf16(af[mt], bf[nt],
                                                                      acc[mt][nt], 0, 0, 0);
    };

    fetch(0, pa0, pb0);
    fetch(32, pa1, pb1);
    for (int k0 = 0; k0 < IN_C; k0 += 64) {
        __syncthreads();                  // prior mfma done reading LDS
        stage(pa0, pb0);
        __syncthreads();                  // staging visible
        if (k0 + 64 < IN_C) fetch(k0 + 64, pa0, pb0);   // in flight over mfma
        mfma_phase();
        __syncthreads();
        stage(pa1, pb1);
        __syncthreads();
        if (k0 + 96 < IN_C) fetch(k0 + 96, pa1, pb1);
        mfma_phase();
    }

    // epilogue: row = quad*4+r, col = l16 (R3-verified mapping)
#pragma unroll
    for (int nt = 0; nt < 4; ++nt) {
        int n = n0 + wn + nt * 16 + l16;
        float bn = bias[n];
#pragma unroll
        for (int mt = 0; mt < 2; ++mt) {
#pragma unroll
            for (int r = 0; r < 4; ++r) {
                int m = m0 + wm + mt * 16 + quad * 4 + r;
                if (m < N_NODES) {
                    float v = acc[mt][nt][r] + bn;
                    C[(size_t)m * HID_C + n] = v > 0.f ? v : 0.f;
                }
            }
        }
    }
}

// ---------------------------------------------------------------------------
// pad W2 [256,50] -> Wp [256,64] (zeros), b2 -> bp[64]
// ---------------------------------------------------------------------------
__global__ void pad_w2(const float* __restrict__ W2, const float* __restrict__ b2,
                       float* __restrict__ Wp, float* __restrict__ bp) {
    int idx = blockIdx.x * blockDim.x + threadIdx.x;
    if (idx < HID_C * PAD_C) {
        int k = idx >> 6, j = idx & 63;
        Wp[idx] = (j < OUT_C) ? W2[k * OUT_C + j] : 0.f;
    }
    if (idx < PAD_C) bp[idx] = (idx < OUT_C) ? b2[idx] : 0.f;
}

// ---------------------------------------------------------------------------
// GEMM2 tiled: h0 = H[M,256] @ Wp[256,64] + bp ; writes fp32 AND bf16 copies
// ---------------------------------------------------------------------------
__global__ __launch_bounds__(256) void gemm2_tiled(const float* __restrict__ H,
                                                   const float* __restrict__ Wp,
                                                   const float* __restrict__ bp,
                                                   float* __restrict__ h0f,
                                                   unsigned short* __restrict__ h0b) {
    __shared__ float As[16][68];
    __shared__ float Bs[16][64];
    const int tid = threadIdx.x;
    const int tx = tid & 15;
    const int ty = tid >> 4;
    const int m0 = blockIdx.x * 64;

    float acc[4][4];
#pragma unroll
    for (int i = 0; i < 4; ++i)
#pragma unroll
        for (int j = 0; j < 4; ++j) acc[i][j] = 0.f;

    const int arow = tid >> 2;
    const int akk  = (tid & 3) << 2;
    const int brow = tid >> 4;
    const int bcol = (tid & 15) << 2;

    for (int k0 = 0; k0 < HID_C; k0 += 16) {
        float4 av = make_float4(0.f, 0.f, 0.f, 0.f);
        int gr = m0 + arow;
        if (gr < N_NODES)
            av = *(const float4*)(H + (size_t)gr * HID_C + k0 + akk);
        As[akk + 0][arow] = av.x;
        As[akk + 1][arow] = av.y;
        As[akk + 2][arow] = av.z;
        As[akk + 3][arow] = av.w;
        float4 bv = *(const float4*)(Wp + (size_t)(k0 + brow) * PAD_C + bcol);
        *(float4*)&Bs[brow][bcol] = bv;
        __syncthreads();

#pragma unroll
        for (int kk = 0; kk < 16; ++kk) {
            float a[4], b[4];
#pragma unroll
            for (int i = 0; i < 4; ++i) a[i] = As[kk][ty * 4 + i];
#pragma unroll
            for (int j = 0; j < 4; ++j) b[j] = Bs[kk][tx * 4 + j];
#pragma unroll
            for (int i = 0; i < 4; ++i)
#pragma unroll
                for (int j = 0; j < 4; ++j) acc[i][j] = fmaf(a[i], b[j], acc[i][j]);
        }
        __syncthreads();
    }

#pragma unroll
    for (int i = 0; i < 4; ++i) {
        int r = m0 + ty * 4 + i;
        if (r >= N_NODES) continue;
#pragma unroll
        for (int j = 0; j < 4; ++j) {
            int c = tx * 4 + j;
            float v = acc[i][j] + bp[c];
            h0f[(size_t)r * PAD_C + c] = v;
            h0b[(size_t)r * PAD_C + c] = f2bf(v);
        }
    }
}

// ---------------------------------------------------------------------------
// CSR build v3 (R7-verified): bucket_scatter -> 98-scan -> fused per-bucket
// hist/scan/scatter. No global histogram, no global fill atomics.
// ---------------------------------------------------------------------------
__global__ __launch_bounds__(256) void bucket_scatter(const int* __restrict__ erow,
                                                      const int* __restrict__ ecol,
                                                      const float* __restrict__ ew,
                                                      int* __restrict__ bfill,
                                                      uint2* __restrict__ buckets) {
    __shared__ int lcnt[NBUCK];
    __shared__ int lbase[NBUCK];
    const int t = threadIdx.x;
    for (int b = t; b < NBUCK; b += 256) lcnt[b] = 0;
    __syncthreads();
    const int e0 = blockIdx.x * PHB_CHUNK;
    const int e1 = min(e0 + PHB_CHUNK, N_EDGES);
    for (int e = e0 + t; e < e1; e += 256)
        atomicAdd(&lcnt[erow[e] >> BSHIFT], 1);
    __syncthreads();
    for (int b = t; b < NBUCK; b += 256) {
        lbase[b] = atomicAdd(&bfill[b], lcnt[b]);
        lcnt[b] = 0;
    }
    __syncthreads();
    for (int e = e0 + t; e < e1; e += 256) {
        int r = erow[e];
        int b = r >> BSHIFT;
        int o = atomicAdd(&lcnt[b], 1);
        int idx = lbase[b] + o;
        if (idx < BCAP) {   // BCAP = mean + 32 sigma: always true
            unsigned packed = ((unsigned)(r - (b << BSHIFT)) << 17) | (unsigned)ecol[e];
            buckets[(size_t)b * BCAP + idx] = make_uint2(packed, __float_as_uint(ew[e]));
        }
    }
}

__global__ __launch_bounds__(128) void bucket_scan(const int* __restrict__ bfill,
                                                   int* __restrict__ bbase,
                                                   int* __restrict__ rowptr) {
    __shared__ int sd[128];
    int t = threadIdx.x;
    int v = (t < NBUCK) ? min(bfill[t], BCAP) : 0;
    sd[t] = v;
    __syncthreads();
    for (int off = 1; off < 128; off <<= 1) {
        int x = (t >= off) ? sd[t - off] : 0;
        __syncthreads();
        sd[t] += x;
        __syncthreads();
    }
    if (t < NBUCK) bbase[t] = sd[t] - v;
    if (t == NBUCK - 1) {
        bbase[NBUCK] = sd[t];
        rowptr[N_NODES] = sd[t];
    }
}

__global__ __launch_bounds__(256) void bucket_csr(const uint2* __restrict__ buckets,
                                                  const int* __restrict__ bfill,
                                                  const int* __restrict__ bbase,
                                                  int* __restrict__ rowptr,
                                                  uint2* __restrict__ edges) {
    __shared__ int hist[512];
    __shared__ int excl[512];
    __shared__ int psum[256];
    const int b = blockIdx.x;
    const int t = threadIdx.x;
    const int n = min(bfill[b], BCAP);
    const uint2* bk = buckets + (size_t)b * BCAP;

    hist[t] = 0; hist[t + 256] = 0;
    __syncthreads();
    for (int i = t; i < n; i += 256)
        atomicAdd(&hist[bk[i].x >> 17], 1);
    __syncthreads();
    int a0 = hist[2 * t], a1 = hist[2 * t + 1];
    psum[t] = a0 + a1;
    __syncthreads();
    for (int off = 1; off < 256; off <<= 1) {
        int x = (t >= off) ? psum[t - off] : 0;
        __syncthreads();
        psum[t] += x;
        __syncthreads();
    }
    int pe = psum[t] - (a0 + a1);
    excl[2 * t] = pe;
    excl[2 * t + 1] = pe + a0;
    __syncthreads();
    const int base = bbase[b];
#pragma unroll
    for (int k = 0; k < 2; ++k) {
        int lr = t + k * 256;
        int r = (b << BSHIFT) + lr;
        if (r < N_NODES) rowptr[r] = base + excl[lr];
    }
    hist[t] = 0; hist[t + 256] = 0;
    __syncthreads();
    for (int i = t; i < n; i += 256) {
        uint2 ed = bk[i];
        int lr = ed.x >> 17;
        int pos = base + excl[lr] + atomicAdd(&hist[lr], 1);
        edges[pos] = make_uint2(ed.x & 0x1FFFFu, ed.y);
    }
}

// ---------------------------------------------------------------------------
// Propagation (R6-verified prop8): 8 lanes x 16 B cover one 128 B row -> one
// gather serves 8 edges; x2 unroll; xor(8/16/32) all-reduce; LAST layer
// fuses log_softmax and writes d_out directly.
// ---------------------------------------------------------------------------
template <bool LAST>
__global__ __launch_bounds__(256) void prop8(const int* __restrict__ rowptr,
                                             const uint2* __restrict__ edges,
                                             const unsigned short* __restrict__ hin,
                                             const float* __restrict__ h0f,
                                             unsigned short* __restrict__ hout_b,
                                             float* __restrict__ out_f) {
    int wid = (blockIdx.x * blockDim.x + threadIdx.x) >> 6;
    if (wid >= N_NODES) return;
    int lane = threadIdx.x & 63;
    int slot = lane >> 3;
    int lc   = lane & 7;
    int s = rowptr[wid], e = rowptr[wid + 1];

    float acc0[8], acc1[8];
#pragma unroll
    for (int k = 0; k < 8; ++k) { acc0[k] = 0.f; acc1[k] = 0.f; }

    int i = s;
    for (; i + 16 <= e; i += 16) {
        uint2 cw0 = edges[i + slot];
        uint2 cw1 = edges[i + 8 + slot];
        uint4 hv0 = *(const uint4*)((const char*)hin + ((size_t)cw0.x << 7) + lc * 16);
        uint4 hv1 = *(const uint4*)((const char*)hin + ((size_t)cw1.x << 7) + lc * 16);
        float w0 = __uint_as_float(cw0.y);
        float w1 = __uint_as_float(cw1.y);
        acc0[0] = fmaf(w0, __uint_as_float(hv0.x << 16),         acc0[0]);
        acc0[1] = fmaf(w0, __uint_as_float(hv0.x & 0xffff0000u), acc0[1]);
        acc0[2] = fmaf(w0, __uint_as_float(hv0.y << 16),         acc0[2]);
        acc0[3] = fmaf(w0, __uint_as_float(hv0.y & 0xffff0000u), acc0[3]);
        acc0[4] = fmaf(w0, __uint_as_float(hv0.z << 16),         acc0[4]);
        acc0[5] = fmaf(w0, __uint_as_float(hv0.z & 0xffff0000u), acc0[5]);
        acc0[6] = fmaf(w0, __uint_as_float(hv0.w << 16),         acc0[6]);
        acc0[7] = fmaf(w0, __uint_as_float(hv0.w & 0xffff0000u), acc0[7]);
        acc1[0] = fmaf(w1, __uint_as_float(hv1.x << 16),         acc1[0]);
        acc1[1] = fmaf(w1, __uint_as_float(hv1.x & 0xffff0000u), acc1[1]);
        acc1[2] = fmaf(w1, __uint_as_float(hv1.y << 16),         acc1[2]);
        acc1[3] = fmaf(w1, __uint_as_float(hv1.y & 0xffff0000u), acc1[3]);
        acc1[4] = fmaf(w1, __uint_as_float(hv1.z << 16),         acc1[4]);
        acc1[5] = fmaf(w1, __uint_as_float(hv1.z & 0xffff0000u), acc1[5]);
        acc1[6] = fmaf(w1, __uint_as_float(hv1.w << 16),         acc1[6]);
        acc1[7] = fmaf(w1, __uint_as_float(hv1.w & 0xffff0000u), acc1[7]);
    }
    for (; i < e; i += 8) {
        int idx = i + slot;
        uint2 cw = (idx < e) ? edges[idx] : make_uint2(0u, 0u);
        float w  = (idx < e) ? __uint_as_float(cw.y) : 0.f;
        uint4 hv = *(const uint4*)((const char*)hin + ((size_t)cw.x << 7) + lc * 16);
        acc0[0] = fmaf(w, __uint_as_float(hv.x << 16),         acc0[0]);
        acc0[1] = fmaf(w, __uint_as_float(hv.x & 0xffff0000u), acc0[1]);
        acc0[2] = fmaf(w, __uint_as_float(hv.y << 16),         acc0[2]);
        acc0[3] = fmaf(w, __uint_as_float(hv.y & 0xffff0000u), acc0[3]);
        acc0[4] = fmaf(w, __uint_as_float(hv.z << 16),         acc0[4]);
        acc0[5] = fmaf(w, __uint_as_float(hv.z & 0xffff0000u), acc0[5]);
        acc0[6] = fmaf(w, __uint_as_float(hv.w << 16),         acc0[6]);
        acc0[7] = fmaf(w, __uint_as_float(hv.w & 0xffff0000u), acc0[7]);
    }

    float r[8];
#pragma unroll
    for (int k = 0; k < 8; ++k) {
        float v = acc0[k] + acc1[k];
        v += __shfl_xor(v, 8, 64);
        v += __shfl_xor(v, 16, 64);
        v += __shfl_xor(v, 32, 64);
        r[k] = v;
    }

    size_t off = (size_t)wid * PAD_C + lc * 8;
    float4 h0a = *(const float4*)(h0f + off);
    float4 h0b4 = *(const float4*)(h0f + off + 4);
    r[0] = 0.9f * r[0] + 0.1f * h0a.x;  r[1] = 0.9f * r[1] + 0.1f * h0a.y;
    r[2] = 0.9f * r[2] + 0.1f * h0a.z;  r[3] = 0.9f * r[3] + 0.1f * h0a.w;
    r[4] = 0.9f * r[4] + 0.1f * h0b4.x; r[5] = 0.9f * r[5] + 0.1f * h0b4.y;
    r[6] = 0.9f * r[6] + 0.1f * h0b4.z; r[7] = 0.9f * r[7] + 0.1f * h0b4.w;

    if (!LAST) {
        if (slot == 0) {
            uint4 u;
            u.x = ((unsigned)f2bf(r[1]) << 16) | f2bf(r[0]);
            u.y = ((unsigned)f2bf(r[3]) << 16) | f2bf(r[2]);
            u.z = ((unsigned)f2bf(r[5]) << 16) | f2bf(r[4]);
            u.w = ((unsigned)f2bf(r[7]) << 16) | f2bf(r[6]);
            *(uint4*)((char*)hout_b + ((size_t)wid << 7) + lc * 16) = u;
        }
    } else {
        int ch0 = lc * 8;
        float m = -INFINITY;
#pragma unroll
        for (int k = 0; k < 8; ++k) if (ch0 + k < OUT_C) m = fmaxf(m, r[k]);
        m = fmaxf(m, __shfl_xor(m, 1, 64));
        m = fmaxf(m, __shfl_xor(m, 2, 64));
        m = fmaxf(m, __shfl_xor(m, 4, 64));
        float ss = 0.f;
#pragma unroll
        for (int k = 0; k < 8; ++k) if (ch0 + k < OUT_C) ss += __expf(r[k] - m);
        ss += __shfl_xor(ss, 1, 64);
        ss += __shfl_xor(ss, 2, 64);
        ss += __shfl_xor(ss, 4, 64);
        float lse = __logf(ss);
        if (slot == 0) {
#pragma unroll
            for (int k = 0; k < 8; ++k)
                if (ch0 + k < OUT_C)
                    out_f[(size_t)wid * OUT_C + ch0 + k] = (r[k] - m) - lse;
        }
    }
}

// ---------------------------------------------------------------------------
extern "C" void kernel_launch(void* const* d_in, const int* in_sizes, int n_in,
                              void* d_out, int out_size, void* d_ws, size_t ws_size,
                              hipStream_t stream) {
    const float* x    = (const float*)d_in[0];
    const int*   erow = (const int*)d_in[1];
    const int*   ecol = (const int*)d_in[2];
    const float* ew   = (const float*)d_in[3];
    const float* W1   = (const float*)d_in[4];
    const float* b1   = (const float*)d_in[5];
    const float* W2   = (const float*)d_in[6];
    const float* b2   = (const float*)d_in[7];
    float* out = (float*)d_out;

    char* p = (char*)d_ws;
    auto alloc = [&](size_t bytes) {
        char* r = p;
        p += (bytes + 255) & ~(size_t)255;
        return r;
    };
    char*  h_hid_raw = alloc((size_t)N_NODES * HID_C * 4);        // 51.2 MB region
    float* h_hid  = (float*)h_hid_raw;
    float* h0f    = (float*)alloc((size_t)N_NODES * PAD_C * 4);   // 12.8 MB
    unsigned short* h0b = (unsigned short*)alloc((size_t)N_NODES * PAD_C * 2); // 6.4 MB
    uint2* edges  = (uint2*)alloc((size_t)N_EDGES * 8);           // 12.8 MB packed CSR
    int*   rowptr = (int*)alloc((size_t)(N_NODES + 1) * 4);
    int*   bfill  = (int*)alloc((size_t)NBUCK * 4);
    int*   bbase  = (int*)alloc((size_t)(NBUCK + 1) * 4);
    float* Wp     = (float*)alloc((size_t)HID_C * PAD_C * 4);
    float* bp     = (float*)alloc((size_t)PAD_C * 4);
    unsigned short* Wt = (unsigned short*)alloc((size_t)HID_C * IN_C * 2);
    // --- aliases onto h_hid region (sequential lifetimes, stream-ordered):
    uint2* buckets = (uint2*)h_hid_raw;                                       // 16.1 MB (CSR build)
    unsigned short* ha = (unsigned short*)h_hid_raw;                          // 6.4 MB (prop)
    unsigned short* hb = (unsigned short*)(h_hid_raw + (size_t)N_NODES * PAD_C * 2); // 6.4 MB

    hipMemsetAsync(bfill, 0, (size_t)NBUCK * 4, stream);

    // CSR build (v3)
    bucket_scatter<<<PHB_BLOCKS, 256, 0, stream>>>(erow, ecol, ew, bfill, buckets);
    bucket_scan<<<1, 128, 0, stream>>>(bfill, bbase, rowptr);
    bucket_csr<<<NBUCK, 256, 0, stream>>>(buckets, bfill, bbase, rowptr, edges);

    // MLP
    transpose_w1<<<dim3(IN_C / 32, HID_C / 32), 256, 0, stream>>>(W1, Wt);
    gemm1_mfma<<<dim3((N_NODES + 63) / 64, HID_C / 128), 256, 0, stream>>>(x, Wt, b1, h_hid);
    pad_w2<<<(HID_C * PAD_C + 255) / 256, 256, 0, stream>>>(W2, b2, Wp, bp);
    gemm2_tiled<<<(N_NODES + 63) / 64, 256, 0, stream>>>(h_hid, Wp, bp, h0f, h0b);

    // Propagation x10 (bf16 ping-pong; last layer fuses log_softmax -> out)
    const int prop_blocks = (N_NODES * 64 + 255) / 256;
    const unsigned short* cur = h0b;
    unsigned short* nxt = ha;
    for (int l = 0; l < NUM_LAYERS - 1; ++l) {
        prop8<false><<<prop_blocks, 256, 0, stream>>>(rowptr, edges, cur, h0f,
                                                      nxt, nullptr);
        const unsigned short* t = nxt;
        nxt = (nxt == ha) ? hb : ha;
        cur = t;
    }
    prop8<true><<<prop_blocks, 256, 0, stream>>>(rowptr, edges, cur, h0f,
                                                 nullptr, out);
}